// Round 13
// baseline (274.929 us; speedup 1.0000x reference)
//
#include <hip/hip_runtime.h>

#define NB 8
#define NN 10000
#define NE 160000
#define NNODES (NB*NN)          // 80000
#define NEDGE (NB*NE)           // 1280000
#define FIN 5
#define HID 128
#define EMB 256
#define ALAST 10
#define PROJ_IN (HID*5 + ALAST + 1)  // 651
#define NPOS 40                      // 5 positions x 8 batches
#define E0CAP 256                    // in-edges kept per position node
#define DUPCAP (NPOS*E0CAP)          // 10240 candidate T1 claims
#define TCAP (NPOS + DUPCAP)         // 10280 max T slots (realistically ~720)
#define E1CAP 131072                 // layer-1 edge entries (realistically ~13k)

// counters layout: cnts[0]=nT, cnts[1]=nDup, cnts[2]=e1cnt, cnts[3..42]=e0cnt[40]
#define C_NT 0
#define C_NDUP 1
#define C_E1 2
#define C_E0 3

// Mark the 40 position nodes; in-wave ballot dedupe (no global round-trips).
__global__ void k_mark(const int* __restrict__ avail, const int* __restrict__ pos,
                       int* __restrict__ mark, int* __restrict__ markT,
                       int* __restrict__ Tnodes, int* __restrict__ need,
                       int* __restrict__ cnts, int2* __restrict__ e1,
                       int* __restrict__ pos2t0, int* __restrict__ posNode) {
    int p = threadIdx.x;                    // 0..63, active p<40
    int n = 0;
    if (p < NPOS) {
        int b = p / 5, pi = p - b*5;
        int node = (pi < 4) ? avail[b*4 + pi] : pos[b];
        n = node + b*NN;
    }
    int firstIdx = p;
    for (int q = 0; q < NPOS; ++q) {
        int nq = __shfl(n, q, 64);
        if (p < NPOS && q < p && nq == n && firstIdx == p) firstIdx = q;
    }
    bool isFirst = (p < NPOS) && (firstIdx == p);
    unsigned long long bal = __ballot(isFirst);
    if (p < NPOS) {
        int slot = __popcll(bal & ((1ull << firstIdx) - 1ull));
        if (isFirst) {
            mark[n] = slot; markT[n] = slot; Tnodes[slot] = n; need[n] = 1;
            int k = atomicAdd(&cnts[C_E1], 1);
            e1[k] = make_int2(n, slot);     // self-loop entry for layer-1 agg
        }
        pos2t0[p] = slot; posNode[p] = n;
    }
    if (p == 0) cnts[C_NT] = __popcll(bal);
}

// pass1: scan dst stream; edges into T0 -> e0 lists (+ candidate sources to dupList)
__global__ __launch_bounds__(256) void k_pass1(const int* __restrict__ edges,
        const int* __restrict__ mark, int* __restrict__ cnts,
        int* __restrict__ e0, int* __restrict__ dupList) {
    int idx = blockIdx.x*256 + threadIdx.x;         // 0..NEDGE/4-1
    int g = idx / (NE/4), w4 = idx - g*(NE/4);
    const int* base = edges + (size_t)g*2*NE;
    int4 d4 = ((const int4*)(base + NE))[w4];
    int gofs = g*NN;
    int dd[4] = {d4.x, d4.y, d4.z, d4.w};
    #pragma unroll
    for (int c = 0; c < 4; ++c) {
        int t0 = mark[gofs + dd[c]];
        if (t0 >= 0) {
            int s = base[4*w4 + c] + gofs;
            int k = atomicAdd(&cnts[C_E0 + t0], 1);
            if (k < E0CAP) e0[t0*E0CAP + k] = s;
            int kd = atomicAdd(&cnts[C_NDUP], 1);
            if (kd < DUPCAP) dupList[kd] = s;
        }
    }
}

// dedup: claim T1 nodes into the T set, append self-loop e1 entries
__global__ void k_dedup(const int* __restrict__ dupList, int* __restrict__ cnts,
                        int* __restrict__ markT, int* __restrict__ Tnodes,
                        int* __restrict__ need, int2* __restrict__ e1) {
    int nd = cnts[C_NDUP]; if (nd > DUPCAP) nd = DUPCAP;
    for (int i = threadIdx.x; i < nd; i += 256) {
        int s = dupList[i];
        int old = atomicCAS(&markT[s], -1, -2);
        if (old == -1) {
            int slot = atomicAdd(&cnts[C_NT], 1);
            if (slot < TCAP) {
                Tnodes[slot] = s;
                need[s] = 1;
                int k = atomicAdd(&cnts[C_E1], 1);
                if (k < E1CAP) e1[k] = make_int2(s, slot);
                markT[s] = slot;
            }   // else leave -2 (excluded everywhere)
        }
    }
}

// pass2: edges into T -> e1 entries; mark sources as needing a degree
__global__ __launch_bounds__(256) void k_pass2(const int* __restrict__ edges,
        const int* __restrict__ markT, int* __restrict__ need,
        int* __restrict__ cnts, int2* __restrict__ e1) {
    int idx = blockIdx.x*256 + threadIdx.x;
    int g = idx / (NE/4), w4 = idx - g*(NE/4);
    const int* base = edges + (size_t)g*2*NE;
    int4 d4 = ((const int4*)(base + NE))[w4];
    int gofs = g*NN;
    int dd[4] = {d4.x, d4.y, d4.z, d4.w};
    #pragma unroll
    for (int c = 0; c < 4; ++c) {
        int ts = markT[gofs + dd[c]];
        if (ts >= 0) {
            int s = base[4*w4 + c] + gofs;
            need[s] = 1;
            int k = atomicAdd(&cnts[C_E1], 1);
            if (k < E1CAP) e1[k] = make_int2(s, ts);
        }
    }
}

// pass3: degree count, filtered to needed nodes only
__global__ __launch_bounds__(256) void k_pass3(const int* __restrict__ edges,
        const int* __restrict__ need, int* __restrict__ degCnt) {
    int idx = blockIdx.x*256 + threadIdx.x;
    int g = idx / (NE/4), w4 = idx - g*(NE/4);
    int4 d4 = ((const int4*)(edges + (size_t)g*2*NE + NE))[w4];
    int gofs = g*NN;
    int dd[4] = {d4.x, d4.y, d4.z, d4.w};
    #pragma unroll
    for (int c = 0; c < 4; ++c) {
        int n = gofs + dd[c];
        if (need[n]) atomicAdd(&degCnt[n], 1);
    }
}

// aggT: layer-1 aggregation at T nodes via fp atomics (entries incl. self-loops)
__global__ __launch_bounds__(256) void k_aggT(const int2* __restrict__ e1,
        const int* __restrict__ cnts, const int* __restrict__ degCnt,
        const float* __restrict__ xg, float* __restrict__ axT) {
    int m = cnts[C_E1]; if (m > E1CAP) m = E1CAP;
    for (int i = blockIdx.x*256 + threadIdx.x; i < m; i += gridDim.x*256) {
        int2 en = e1[i];
        float dv = rsqrtf(1.0f + (float)degCnt[en.x]);
        const float* xr = xg + (size_t)en.x*FIN;
        float* at = axT + (size_t)en.y*FIN;
        #pragma unroll
        for (int f = 0; f < FIN; ++f) unsafeAtomicAdd(&at[f], xr[f]*dv);
    }
}

// Fused layer-1 dense + layer-2 dense over T slots only (<= ~720 rows).
// Same tile structure as the known-good k_h12 (128 rows x 64 cols, col-split).
#define KC 32
__global__ __launch_bounds__(256) void k_h12T(
        const float* __restrict__ axT, const int* __restrict__ Tnodes,
        const int* __restrict__ degCnt, const int* __restrict__ cnts,
        const float* __restrict__ W1, const float* __restrict__ b1,
        const float* __restrict__ W2, float* __restrict__ hsT) {
    __shared__ float axs[FIN][128];
    __shared__ float w1s[FIN][128];
    __shared__ float b1s[128];
    __shared__ float dvs[128];
    __shared__ float xs[KC*128];
    __shared__ float wt[KC*64];
    int ntv = cnts[C_NT]; if (ntv > TCAP) ntv = TCAP;
    int jb  = blockIdx.x & 1;
    int m0g = (blockIdx.x >> 1) * 128;
    if (m0g >= ntv) return;
    int tid = threadIdx.x;
    if (tid < 128) {
        b1s[tid] = b1[tid];
        #pragma unroll
        for (int f = 0; f < FIN; ++f) w1s[f][tid] = W1[tid*FIN + f];
    } else {
        int r2 = tid - 128;
        int row = m0g + r2;
        int ok = row < ntv;
        int node = ok ? Tnodes[row] : 0;
        dvs[r2] = ok ? rsqrtf(1.0f + (float)degCnt[node]) : 0.0f;
        #pragma unroll
        for (int f = 0; f < FIN; ++f) axs[f][r2] = axT[(size_t)row*FIN + f];
    }
    int tx = tid & 15, ty = tid >> 4;
    int m0 = ty*8;
    int j0 = tx*4;
    int r  = tid >> 1;
    int kq = (tid & 1) * 16;
    int rw  = tid >> 2;
    int kqw = (tid & 3) * 8;
    float a[8][4];
    #pragma unroll
    for (int i = 0; i < 8; ++i)
        #pragma unroll
        for (int j = 0; j < 4; ++j) a[i][j] = 0.f;
    __syncthreads();
    float axr[FIN];
    float dvr = dvs[r];
    #pragma unroll
    for (int f = 0; f < FIN; ++f) axr[f] = axs[f][r] * dvr;

    for (int kh = 0; kh < 128; kh += KC) {
        float4 wv0 = *(const float4*)&W2[(size_t)(jb*64 + rw)*128 + kh + kqw];
        float4 wv1 = *(const float4*)&W2[(size_t)(jb*64 + rw)*128 + kh + kqw + 4];
        float hv[16];
        #pragma unroll
        for (int kk = 0; kk < 16; ++kk) {
            int k1 = kh + kq + kk;
            float sv = b1s[k1];
            #pragma unroll
            for (int f = 0; f < FIN; ++f) sv += axr[f]*w1s[f][k1];
            hv[kk] = fmaxf(sv, 0.0f);
        }
        __syncthreads();
        #pragma unroll
        for (int kk = 0; kk < 16; ++kk) xs[(kq+kk)*128 + r] = hv[kk];
        wt[(kqw+0)*64 + rw] = wv0.x;
        wt[(kqw+1)*64 + rw] = wv0.y;
        wt[(kqw+2)*64 + rw] = wv0.z;
        wt[(kqw+3)*64 + rw] = wv0.w;
        wt[(kqw+4)*64 + rw] = wv1.x;
        wt[(kqw+5)*64 + rw] = wv1.y;
        wt[(kqw+6)*64 + rw] = wv1.z;
        wt[(kqw+7)*64 + rw] = wv1.w;
        __syncthreads();
        for (int k = 0; k < KC; ++k) {
            float4 xa = *(const float4*)&xs[k*128 + m0];
            float4 xb = *(const float4*)&xs[k*128 + m0 + 4];
            float4 wa = *(const float4*)&wt[k*64 + j0];
            float xr[8] = {xa.x,xa.y,xa.z,xa.w,xb.x,xb.y,xb.z,xb.w};
            #pragma unroll
            for (int i = 0; i < 8; ++i) {
                a[i][0] += xr[i]*wa.x;
                a[i][1] += xr[i]*wa.y;
                a[i][2] += xr[i]*wa.z;
                a[i][3] += xr[i]*wa.w;
            }
        }
    }
    #pragma unroll
    for (int i = 0; i < 8; ++i) {
        int row = m0g + m0 + i;
        if (row < ntv) {
            float dv = dvs[m0 + i];
            float4 v0 = make_float4(a[i][0]*dv, a[i][1]*dv, a[i][2]*dv, a[i][3]*dv);
            *(float4*)&hsT[(size_t)row*HID + jb*64 + j0] = v0;
        }
    }
}

// layer-2 aggregation at the 40 positions, from compact hsT rows
__global__ __launch_bounds__(128) void k_aggPT(
        const int* __restrict__ pos2t0, const int* __restrict__ posNode,
        const int* __restrict__ cnts, const int* __restrict__ e0,
        const int* __restrict__ markT, const float* __restrict__ hsT,
        const int* __restrict__ degCnt, const float* __restrict__ b2,
        float* __restrict__ cx40) {
    int p = blockIdx.x;
    int f = threadIdx.x;
    int n = posNode[p];
    int t0 = pos2t0[p];
    float acc = hsT[(size_t)t0*HID + f];        // self-loop term
    int m = cnts[C_E0 + t0]; if (m > E0CAP) m = E0CAP;
    for (int j = 0; j < m; ++j) {
        int s = e0[t0*E0CAP + j];
        int ts = markT[s];
        if (ts >= 0) acc += hsT[(size_t)ts*HID + f];
    }
    float dv = rsqrtf(1.0f + (float)degCnt[n]);
    cx40[(size_t)p*HID + f] = fmaxf(acc*dv + b2[f], 0.0f);
}

// MLP1: block per (batch, 16-output group); 16 lanes per output, shuffle-reduce.
__global__ __launch_bounds__(256) void k_mlp1(
        const float* __restrict__ cx40, const float* __restrict__ actions,
        const float* __restrict__ steps,
        const float* __restrict__ Wp1, const float* __restrict__ bp1,
        float* __restrict__ hm) {
    int b  = blockIdx.x >> 4;
    int jg = blockIdx.x & 15;
    int t  = threadIdx.x;
    __shared__ float c[PROJ_IN];
    for (int i = t; i < 5*HID; i += 256)
        c[i] = cx40[(size_t)b*5*HID + i];
    if (t < ALAST) c[5*HID + t] = actions[b*ALAST + t];
    if (t == ALAST) c[5*HID + ALAST] = steps[b];
    __syncthreads();
    int o = t >> 4, sub = t & 15;
    int j = jg*16 + o;
    const float* wr = Wp1 + (size_t)j*PROJ_IN;
    float s = 0.f;
    for (int k = sub; k < PROJ_IN; k += 16) s += c[k]*wr[k];
    #pragma unroll
    for (int d = 8; d; d >>= 1) s += __shfl_down(s, d, 16);
    if (sub == 0) hm[b*EMB + j] = fmaxf(s + bp1[j], 0.f);
}

// MLP2
__global__ __launch_bounds__(256) void k_mlp2(
        const float* __restrict__ hm, const float* __restrict__ Wp2,
        const float* __restrict__ bp2, float* __restrict__ out) {
    int b  = blockIdx.x >> 4;
    int jg = blockIdx.x & 15;
    int t  = threadIdx.x;
    __shared__ float c[EMB];
    if (t < EMB) c[t] = hm[b*EMB + t];
    __syncthreads();
    int o = t >> 4, sub = t & 15;
    int j = jg*16 + o;
    const float* wr = Wp2 + (size_t)j*EMB;
    float s = 0.f;
    for (int k = sub; k < EMB; k += 16) s += c[k]*wr[k];
    #pragma unroll
    for (int d = 8; d; d >>= 1) s += __shfl_down(s, d, 16);
    if (sub == 0) out[b*EMB + j] = s + bp2[j];
}

extern "C" void kernel_launch(void* const* d_in, const int* in_sizes, int n_in,
                              void* d_out, int out_size, void* d_ws, size_t ws_size,
                              hipStream_t stream) {
    const float* graph_x = (const float*)d_in[0];
    const int*   edges   = (const int*)d_in[1];
    const int*   pos     = (const int*)d_in[2];
    const int*   avail   = (const int*)d_in[3];
    const float* actions = (const float*)d_in[4];
    const float* steps   = (const float*)d_in[5];
    const float* W1  = (const float*)d_in[6];
    const float* b1  = (const float*)d_in[7];
    const float* W2  = (const float*)d_in[8];
    const float* b2  = (const float*)d_in[9];
    const float* Wp1 = (const float*)d_in[10];
    const float* bp1 = (const float*)d_in[11];
    const float* Wp2 = (const float*)d_in[12];
    const float* bp2 = (const float*)d_in[13];
    float* out = (float*)d_out;

    char* ws = (char*)d_ws;
    size_t off = 0;
    #define ALLOC(ptrname, type, nelem) \
        type* ptrname = (type*)(ws + off); off = (off + (size_t)(nelem)*sizeof(type) + 255) & ~(size_t)255;
    // memset A region (-1): mark, markT
    ALLOC(mark,    int,   NNODES)
    ALLOC(markT,   int,   NNODES)
    // memset B region (0): need, degCnt, cnts, axT
    ALLOC(need,    int,   NNODES)
    ALLOC(degCnt,  int,   NNODES)
    ALLOC(cnts,    int,   64)
    ALLOC(axT,     float, (size_t)(TCAP+128)*FIN)
    char* msB_end = ws + off;
    // un-cleared scratch
    ALLOC(dupList, int,   DUPCAP)
    ALLOC(Tnodes,  int,   TCAP)
    ALLOC(pos2t0,  int,   NPOS)
    ALLOC(posNode, int,   NPOS)
    ALLOC(e0,      int,   NPOS*E0CAP)
    ALLOC(e1,      int2,  E1CAP)
    ALLOC(hsT,     float, (size_t)TCAP*HID)
    ALLOC(cx40,    float, (size_t)NPOS*HID)
    ALLOC(hm,      float, (size_t)NB*EMB)
    #undef ALLOC

    hipMemsetAsync(mark, 0xFF, (char*)need - (char*)mark, stream);           // mark, markT = -1
    hipMemsetAsync(need, 0x00, (size_t)(msB_end - (char*)need), stream);     // need..axT = 0

    k_mark<<<1, 64, 0, stream>>>(avail, pos, mark, markT, Tnodes, need, cnts, e1,
                                 pos2t0, posNode);
    k_pass1<<<NEDGE/4/256, 256, 0, stream>>>(edges, mark, cnts, e0, dupList);
    k_dedup<<<1, 256, 0, stream>>>(dupList, cnts, markT, Tnodes, need, e1);
    k_pass2<<<NEDGE/4/256, 256, 0, stream>>>(edges, markT, need, cnts, e1);
    k_pass3<<<NEDGE/4/256, 256, 0, stream>>>(edges, need, degCnt);
    k_aggT<<<128, 256, 0, stream>>>(e1, cnts, degCnt, graph_x, axT);
    k_h12T<<<2*((TCAP+127)/128), 256, 0, stream>>>(axT, Tnodes, degCnt, cnts,
                                                   W1, b1, W2, hsT);
    k_aggPT<<<NPOS, 128, 0, stream>>>(pos2t0, posNode, cnts, e0, markT, hsT,
                                      degCnt, b2, cx40);
    k_mlp1<<<NB*16, 256, 0, stream>>>(cx40, actions, steps, Wp1, bp1, hm);
    k_mlp2<<<NB*16, 256, 0, stream>>>(hm, Wp2, bp2, out);
}

// Round 14
// 209.115 us; speedup vs baseline: 1.3147x; 1.3147x over previous
//
#include <hip/hip_runtime.h>

#define NB 8
#define NN 10000
#define NE 160000
#define NNODES (NB*NN)          // 80000
#define NEDGE (NB*NE)           // 1280000
#define FIN 5
#define HID 128
#define EMB 256
#define ALAST 10
#define PROJ_IN (HID*5 + ALAST + 1)  // 651
#define NPOS 40                      // 5 positions x 8 batches
#define E0CAP 256                    // in-edges kept per position node
#define TCAP (NPOS + NPOS*E0CAP)     // 10280 max T slots (realistically ~720)

// cnts: [0]=nT; per-position e0 counters at stride-16 ints (64B) to avoid
// same-cache-line RMW serialization.
#define C_NT 0
#define C_E0(t) (8 + (t)*16)

// Mark the 40 position nodes; in-wave ballot dedupe.
__global__ void k_mark(const int* __restrict__ avail, const int* __restrict__ pos,
                       int* __restrict__ markT, int* __restrict__ Tnodes,
                       int* __restrict__ need, int* __restrict__ cnts,
                       int* __restrict__ pos2t0, int* __restrict__ posNode) {
    int p = threadIdx.x;                    // 0..63, active p<40
    int n = 0;
    if (p < NPOS) {
        int b = p / 5, pi = p - b*5;
        int node = (pi < 4) ? avail[b*4 + pi] : pos[b];
        n = node + b*NN;
    }
    int firstIdx = p;
    for (int q = 0; q < NPOS; ++q) {
        int nq = __shfl(n, q, 64);
        if (p < NPOS && q < p && nq == n && firstIdx == p) firstIdx = q;
    }
    bool isFirst = (p < NPOS) && (firstIdx == p);
    unsigned long long bal = __ballot(isFirst);
    if (p < NPOS) {
        int slot = __popcll(bal & ((1ull << firstIdx) - 1ull));
        if (isFirst) {
            markT[n] = slot; Tnodes[slot] = n; need[n] = 1;
        }
        pos2t0[p] = slot; posNode[p] = n;
    }
    if (p == 0) cnts[C_NT] = __popcll(bal);
}

// pass1: edges into T0 -> e0 lists (40 padded counters, low contention)
__global__ __launch_bounds__(256) void k_pass1(const int* __restrict__ edges,
        const int* __restrict__ markT, int* __restrict__ cnts,
        int* __restrict__ e0) {
    int idx = blockIdx.x*256 + threadIdx.x;         // 0..NEDGE/4-1
    int g = idx / (NE/4), w4 = idx - g*(NE/4);
    const int* base = edges + (size_t)g*2*NE;
    int4 d4 = ((const int4*)(base + NE))[w4];
    int gofs = g*NN;
    int dd[4] = {d4.x, d4.y, d4.z, d4.w};
    #pragma unroll
    for (int c = 0; c < 4; ++c) {
        int t0 = markT[gofs + dd[c]];
        if (t0 >= 0) {
            int s = base[4*w4 + c] + gofs;
            int k = atomicAdd(&cnts[C_E0(t0)], 1);
            if (k < E0CAP) e0[t0*E0CAP + k] = s;
        }
    }
}

// dedup: claim T1 nodes from the e0 lists; slots via LDS counter (1 block)
__global__ __launch_bounds__(256) void k_dedup(const int* __restrict__ e0,
                        int* __restrict__ cnts, int* __restrict__ markT,
                        int* __restrict__ Tnodes, int* __restrict__ need) {
    __shared__ int lc;
    if (threadIdx.x == 0) lc = 0;
    __syncthreads();
    int base = cnts[C_NT];
    for (int i = threadIdx.x; i < NPOS*E0CAP; i += 256) {
        int t0 = i >> 8, k = i & (E0CAP-1);
        int m = cnts[C_E0(t0)]; if (m > E0CAP) m = E0CAP;
        if (k < m) {
            int s = e0[t0*E0CAP + k];
            if (atomicCAS(&markT[s], -1, -2) == -1) {
                int sl = base + atomicAdd(&lc, 1);     // LDS atomic
                Tnodes[sl] = s;
                need[s] = 1;
                markT[s] = sl;
            }
        }
    }
    __syncthreads();
    if (threadIdx.x == 0) cnts[C_NT] = base + lc;
}

// pass2a: mark sources of edges into T (plain scattered stores, no atomics)
__global__ __launch_bounds__(256) void k_pass2a(const int* __restrict__ edges,
        const int* __restrict__ markT, int* __restrict__ need) {
    int idx = blockIdx.x*256 + threadIdx.x;
    int g = idx / (NE/4), w4 = idx - g*(NE/4);
    const int* base = edges + (size_t)g*2*NE;
    int4 d4 = ((const int4*)(base + NE))[w4];
    int gofs = g*NN;
    int dd[4] = {d4.x, d4.y, d4.z, d4.w};
    #pragma unroll
    for (int c = 0; c < 4; ++c) {
        if (markT[gofs + dd[c]] >= 0)
            need[base[4*w4 + c] + gofs] = 1;
    }
}

// pass3: degree count filtered to needed nodes (distributed atomics)
__global__ __launch_bounds__(256) void k_pass3(const int* __restrict__ edges,
        const int* __restrict__ need, int* __restrict__ degCnt) {
    int idx = blockIdx.x*256 + threadIdx.x;
    int g = idx / (NE/4), w4 = idx - g*(NE/4);
    int4 d4 = ((const int4*)(edges + (size_t)g*2*NE + NE))[w4];
    int gofs = g*NN;
    int dd[4] = {d4.x, d4.y, d4.z, d4.w};
    #pragma unroll
    for (int c = 0; c < 4; ++c) {
        int n = gofs + dd[c];
        if (need[n]) atomicAdd(&degCnt[n], 1);
    }
}

// pass2b: aggregate layer-1 inputs directly at T slots (distributed fp atomics)
__global__ __launch_bounds__(256) void k_pass2b(const int* __restrict__ edges,
        const int* __restrict__ markT, const int* __restrict__ degCnt,
        const float* __restrict__ xg, float* __restrict__ axT) {
    int idx = blockIdx.x*256 + threadIdx.x;
    int g = idx / (NE/4), w4 = idx - g*(NE/4);
    const int* base = edges + (size_t)g*2*NE;
    int4 d4 = ((const int4*)(base + NE))[w4];
    int gofs = g*NN;
    int dd[4] = {d4.x, d4.y, d4.z, d4.w};
    #pragma unroll
    for (int c = 0; c < 4; ++c) {
        int ts = markT[gofs + dd[c]];
        if (ts >= 0) {
            int s = base[4*w4 + c] + gofs;
            float dv = rsqrtf(1.0f + (float)degCnt[s]);
            const float* xr = xg + (size_t)s*FIN;
            float* at = axT + (size_t)ts*FIN;
            #pragma unroll
            for (int f = 0; f < FIN; ++f) unsafeAtomicAdd(&at[f], xr[f]*dv);
        }
    }
}

// Fused layer-1 dense + layer-2 dense over T slots (<= ~720 active rows).
// Self-loop term added during A-tile load: ax = (sum_in + x[n]*dv) * dv.
#define KC 32
__global__ __launch_bounds__(256) void k_h12T(
        const float* __restrict__ axT, const int* __restrict__ Tnodes,
        const int* __restrict__ degCnt, const int* __restrict__ cnts,
        const float* __restrict__ xg,
        const float* __restrict__ W1, const float* __restrict__ b1,
        const float* __restrict__ W2, float* __restrict__ hsT) {
    __shared__ float axs[FIN][128];
    __shared__ float w1s[FIN][128];
    __shared__ float b1s[128];
    __shared__ float dvs[128];
    __shared__ float xs[KC*128];
    __shared__ float wt[KC*64];
    int ntv = cnts[C_NT]; if (ntv > TCAP) ntv = TCAP;
    int jb  = blockIdx.x & 1;
    int m0g = (blockIdx.x >> 1) * 128;
    if (m0g >= ntv) return;
    int tid = threadIdx.x;
    if (tid < 128) {
        b1s[tid] = b1[tid];
        #pragma unroll
        for (int f = 0; f < FIN; ++f) w1s[f][tid] = W1[tid*FIN + f];
    } else {
        int r2 = tid - 128;
        int row = m0g + r2;
        int ok = row < ntv;
        int node = ok ? Tnodes[row] : 0;
        float dvv = ok ? rsqrtf(1.0f + (float)degCnt[node]) : 0.0f;
        dvs[r2] = dvv;
        #pragma unroll
        for (int f = 0; f < FIN; ++f)
            axs[f][r2] = axT[(size_t)row*FIN + f] + xg[(size_t)node*FIN + f]*dvv;
    }
    int tx = tid & 15, ty = tid >> 4;
    int m0 = ty*8;
    int j0 = tx*4;
    int r  = tid >> 1;
    int kq = (tid & 1) * 16;
    int rw  = tid >> 2;
    int kqw = (tid & 3) * 8;
    float a[8][4];
    #pragma unroll
    for (int i = 0; i < 8; ++i)
        #pragma unroll
        for (int j = 0; j < 4; ++j) a[i][j] = 0.f;
    __syncthreads();
    float axr[FIN];
    float dvr = dvs[r];
    #pragma unroll
    for (int f = 0; f < FIN; ++f) axr[f] = axs[f][r] * dvr;

    for (int kh = 0; kh < 128; kh += KC) {
        float4 wv0 = *(const float4*)&W2[(size_t)(jb*64 + rw)*128 + kh + kqw];
        float4 wv1 = *(const float4*)&W2[(size_t)(jb*64 + rw)*128 + kh + kqw + 4];
        float hv[16];
        #pragma unroll
        for (int kk = 0; kk < 16; ++kk) {
            int k1 = kh + kq + kk;
            float sv = b1s[k1];
            #pragma unroll
            for (int f = 0; f < FIN; ++f) sv += axr[f]*w1s[f][k1];
            hv[kk] = fmaxf(sv, 0.0f);
        }
        __syncthreads();
        #pragma unroll
        for (int kk = 0; kk < 16; ++kk) xs[(kq+kk)*128 + r] = hv[kk];
        wt[(kqw+0)*64 + rw] = wv0.x;
        wt[(kqw+1)*64 + rw] = wv0.y;
        wt[(kqw+2)*64 + rw] = wv0.z;
        wt[(kqw+3)*64 + rw] = wv0.w;
        wt[(kqw+4)*64 + rw] = wv1.x;
        wt[(kqw+5)*64 + rw] = wv1.y;
        wt[(kqw+6)*64 + rw] = wv1.z;
        wt[(kqw+7)*64 + rw] = wv1.w;
        __syncthreads();
        for (int k = 0; k < KC; ++k) {
            float4 xa = *(const float4*)&xs[k*128 + m0];
            float4 xb = *(const float4*)&xs[k*128 + m0 + 4];
            float4 wa = *(const float4*)&wt[k*64 + j0];
            float xr[8] = {xa.x,xa.y,xa.z,xa.w,xb.x,xb.y,xb.z,xb.w};
            #pragma unroll
            for (int i = 0; i < 8; ++i) {
                a[i][0] += xr[i]*wa.x;
                a[i][1] += xr[i]*wa.y;
                a[i][2] += xr[i]*wa.z;
                a[i][3] += xr[i]*wa.w;
            }
        }
    }
    #pragma unroll
    for (int i = 0; i < 8; ++i) {
        int row = m0g + m0 + i;
        if (row < ntv) {
            float dv = dvs[m0 + i];
            float4 v0 = make_float4(a[i][0]*dv, a[i][1]*dv, a[i][2]*dv, a[i][3]*dv);
            *(float4*)&hsT[(size_t)row*HID + jb*64 + j0] = v0;
        }
    }
}

// layer-2 aggregation at the 40 positions, from compact hsT rows
__global__ __launch_bounds__(128) void k_aggPT(
        const int* __restrict__ pos2t0, const int* __restrict__ posNode,
        const int* __restrict__ cnts, const int* __restrict__ e0,
        const int* __restrict__ markT, const float* __restrict__ hsT,
        const int* __restrict__ degCnt, const float* __restrict__ b2,
        float* __restrict__ cx40) {
    int p = blockIdx.x;
    int f = threadIdx.x;
    int n = posNode[p];
    int t0 = pos2t0[p];
    float acc = hsT[(size_t)t0*HID + f];        // self-loop term
    int m = cnts[C_E0(t0)]; if (m > E0CAP) m = E0CAP;
    for (int j = 0; j < m; ++j) {
        int s = e0[t0*E0CAP + j];
        int ts = markT[s];
        if (ts >= 0) acc += hsT[(size_t)ts*HID + f];
    }
    float dv = rsqrtf(1.0f + (float)degCnt[n]);
    cx40[(size_t)p*HID + f] = fmaxf(acc*dv + b2[f], 0.0f);
}

// MLP1: block per (batch, 16-output group); 16 lanes per output, shuffle-reduce.
__global__ __launch_bounds__(256) void k_mlp1(
        const float* __restrict__ cx40, const float* __restrict__ actions,
        const float* __restrict__ steps,
        const float* __restrict__ Wp1, const float* __restrict__ bp1,
        float* __restrict__ hm) {
    int b  = blockIdx.x >> 4;
    int jg = blockIdx.x & 15;
    int t  = threadIdx.x;
    __shared__ float c[PROJ_IN];
    for (int i = t; i < 5*HID; i += 256)
        c[i] = cx40[(size_t)b*5*HID + i];
    if (t < ALAST) c[5*HID + t] = actions[b*ALAST + t];
    if (t == ALAST) c[5*HID + ALAST] = steps[b];
    __syncthreads();
    int o = t >> 4, sub = t & 15;
    int j = jg*16 + o;
    const float* wr = Wp1 + (size_t)j*PROJ_IN;
    float s = 0.f;
    for (int k = sub; k < PROJ_IN; k += 16) s += c[k]*wr[k];
    #pragma unroll
    for (int d = 8; d; d >>= 1) s += __shfl_down(s, d, 16);
    if (sub == 0) hm[b*EMB + j] = fmaxf(s + bp1[j], 0.f);
}

// MLP2
__global__ __launch_bounds__(256) void k_mlp2(
        const float* __restrict__ hm, const float* __restrict__ Wp2,
        const float* __restrict__ bp2, float* __restrict__ out) {
    int b  = blockIdx.x >> 4;
    int jg = blockIdx.x & 15;
    int t  = threadIdx.x;
    __shared__ float c[EMB];
    if (t < EMB) c[t] = hm[b*EMB + t];
    __syncthreads();
    int o = t >> 4, sub = t & 15;
    int j = jg*16 + o;
    const float* wr = Wp2 + (size_t)j*EMB;
    float s = 0.f;
    for (int k = sub; k < EMB; k += 16) s += c[k]*wr[k];
    #pragma unroll
    for (int d = 8; d; d >>= 1) s += __shfl_down(s, d, 16);
    if (sub == 0) out[b*EMB + j] = s + bp2[j];
}

extern "C" void kernel_launch(void* const* d_in, const int* in_sizes, int n_in,
                              void* d_out, int out_size, void* d_ws, size_t ws_size,
                              hipStream_t stream) {
    const float* graph_x = (const float*)d_in[0];
    const int*   edges   = (const int*)d_in[1];
    const int*   pos     = (const int*)d_in[2];
    const int*   avail   = (const int*)d_in[3];
    const float* actions = (const float*)d_in[4];
    const float* steps   = (const float*)d_in[5];
    const float* W1  = (const float*)d_in[6];
    const float* b1  = (const float*)d_in[7];
    const float* W2  = (const float*)d_in[8];
    const float* b2  = (const float*)d_in[9];
    const float* Wp1 = (const float*)d_in[10];
    const float* bp1 = (const float*)d_in[11];
    const float* Wp2 = (const float*)d_in[12];
    const float* bp2 = (const float*)d_in[13];
    float* out = (float*)d_out;

    char* ws = (char*)d_ws;
    size_t off = 0;
    #define ALLOC(ptrname, type, nelem) \
        type* ptrname = (type*)(ws + off); off = (off + (size_t)(nelem)*sizeof(type) + 255) & ~(size_t)255;
    // memset A region (-1): markT
    ALLOC(markT,   int,   NNODES)
    // memset B region (0): need, degCnt, cnts, axT
    ALLOC(need,    int,   NNODES)
    ALLOC(degCnt,  int,   NNODES)
    ALLOC(cnts,    int,   1024)
    ALLOC(axT,     float, (size_t)(TCAP+128)*FIN)
    char* msB_end = ws + off;
    // un-cleared scratch
    ALLOC(Tnodes,  int,   TCAP)
    ALLOC(pos2t0,  int,   NPOS)
    ALLOC(posNode, int,   NPOS)
    ALLOC(e0,      int,   NPOS*E0CAP)
    ALLOC(hsT,     float, (size_t)TCAP*HID)
    ALLOC(cx40,    float, (size_t)NPOS*HID)
    ALLOC(hm,      float, (size_t)NB*EMB)
    #undef ALLOC

    hipMemsetAsync(markT, 0xFF, (char*)need - (char*)markT, stream);       // markT = -1
    hipMemsetAsync(need, 0x00, (size_t)(msB_end - (char*)need), stream);   // need..axT = 0

    k_mark<<<1, 64, 0, stream>>>(avail, pos, markT, Tnodes, need, cnts,
                                 pos2t0, posNode);
    k_pass1<<<NEDGE/4/256, 256, 0, stream>>>(edges, markT, cnts, e0);
    k_dedup<<<1, 256, 0, stream>>>(e0, cnts, markT, Tnodes, need);
    k_pass2a<<<NEDGE/4/256, 256, 0, stream>>>(edges, markT, need);
    k_pass3<<<NEDGE/4/256, 256, 0, stream>>>(edges, need, degCnt);
    k_pass2b<<<NEDGE/4/256, 256, 0, stream>>>(edges, markT, degCnt, graph_x, axT);
    k_h12T<<<2*((TCAP+127)/128), 256, 0, stream>>>(axT, Tnodes, degCnt, cnts,
                                                   graph_x, W1, b1, W2, hsT);
    k_aggPT<<<NPOS, 128, 0, stream>>>(pos2t0, posNode, cnts, e0, markT, hsT,
                                      degCnt, b2, cx40);
    k_mlp1<<<NB*16, 256, 0, stream>>>(cx40, actions, steps, Wp1, bp1, hm);
    k_mlp2<<<NB*16, 256, 0, stream>>>(hm, Wp2, bp2, out);
}

// Round 15
// 173.071 us; speedup vs baseline: 1.5885x; 1.2083x over previous
//
#include <hip/hip_runtime.h>

#define NB 8
#define NN 10000
#define NE 160000
#define NNODES (NB*NN)          // 80000
#define NEDGE (NB*NE)           // 1280000
#define FIN 5
#define HID 128
#define EMB 256
#define ALAST 10
#define PROJ_IN (HID*5 + ALAST + 1)  // 651
#define NPOS 40                      // 5 positions x 8 batches
#define E0CAP 256                    // in-edges kept per position node
#define TCAP (NPOS + NPOS*E0CAP)     // 10280 max T slots (realistically ~720)

// markT encoding: -1 none, >=0 T slot, -2 transient CAS claim, -3 degree-needed-only
// cnts: [0]=nT; per-position e0 counters at stride-16 ints (64B padded).
#define C_NT 0
#define C_E0(t) (8 + (t)*16)

// Mark the 40 position nodes; in-wave ballot dedupe.
__global__ void k_mark(const int* __restrict__ avail, const int* __restrict__ pos,
                       int* __restrict__ markT, int* __restrict__ Tnodes,
                       int* __restrict__ cnts,
                       int* __restrict__ pos2t0, int* __restrict__ posNode) {
    int p = threadIdx.x;                    // 0..63, active p<40
    int n = 0;
    if (p < NPOS) {
        int b = p / 5, pi = p - b*5;
        int node = (pi < 4) ? avail[b*4 + pi] : pos[b];
        n = node + b*NN;
    }
    int firstIdx = p;
    for (int q = 0; q < NPOS; ++q) {
        int nq = __shfl(n, q, 64);
        if (p < NPOS && q < p && nq == n && firstIdx == p) firstIdx = q;
    }
    bool isFirst = (p < NPOS) && (firstIdx == p);
    unsigned long long bal = __ballot(isFirst);
    if (p < NPOS) {
        int slot = __popcll(bal & ((1ull << firstIdx) - 1ull));
        if (isFirst) {
            markT[n] = slot; Tnodes[slot] = n;
        }
        pos2t0[p] = slot; posNode[p] = n;
    }
    if (p == 0) cnts[C_NT] = __popcll(bal);
}

// pass1: edges into T0 -> e0 lists (40 padded counters, low contention)
__global__ __launch_bounds__(256) void k_pass1(const int* __restrict__ edges,
        const int* __restrict__ markT, int* __restrict__ cnts,
        int* __restrict__ e0) {
    int idx = blockIdx.x*256 + threadIdx.x;         // 0..NEDGE/4-1
    int g = idx / (NE/4), w4 = idx - g*(NE/4);
    const int* base = edges + (size_t)g*2*NE;
    int4 d4 = ((const int4*)(base + NE))[w4];
    int gofs = g*NN;
    int dd[4] = {d4.x, d4.y, d4.z, d4.w};
    #pragma unroll
    for (int c = 0; c < 4; ++c) {
        int t0 = markT[gofs + dd[c]];
        if (t0 >= 0) {
            int s = base[4*w4 + c] + gofs;
            int k = atomicAdd(&cnts[C_E0(t0)], 1);
            if (k < E0CAP) e0[t0*E0CAP + k] = s;
        }
    }
}

// dedup, parallel: 40 blocks (one per e0 list), one item per thread.
// CAS-claim -> LDS winner count -> leader reserves a slot range (1 global
// atomic per block) -> winners write Tnodes/markT.
__global__ __launch_bounds__(256) void k_dedup(const int* __restrict__ e0,
                        int* __restrict__ cnts, int* __restrict__ markT,
                        int* __restrict__ Tnodes) {
    __shared__ int lc, base;
    int t0 = blockIdx.x;
    if (threadIdx.x == 0) lc = 0;
    __syncthreads();
    int m = cnts[C_E0(t0)]; if (m > E0CAP) m = E0CAP;
    int s = -1, myIdx = -1;
    if ((int)threadIdx.x < m) {
        s = e0[t0*E0CAP + threadIdx.x];
        if (atomicCAS(&markT[s], -1, -2) == -1)
            myIdx = atomicAdd(&lc, 1);              // LDS atomic
    }
    __syncthreads();
    if (threadIdx.x == 0 && lc > 0) base = atomicAdd(&cnts[C_NT], lc);
    __syncthreads();
    if (myIdx >= 0) {
        int slot = base + myIdx;                    // < TCAP by construction
        Tnodes[slot] = s;
        markT[s] = slot;
    }
}

// pass2a: mark sources of edges into T as degree-needed (plain stores)
__global__ __launch_bounds__(256) void k_pass2a(const int* __restrict__ edges,
        int* __restrict__ markT) {
    int idx = blockIdx.x*256 + threadIdx.x;
    int g = idx / (NE/4), w4 = idx - g*(NE/4);
    const int* base = edges + (size_t)g*2*NE;
    int4 d4 = ((const int4*)(base + NE))[w4];
    int gofs = g*NN;
    int dd[4] = {d4.x, d4.y, d4.z, d4.w};
    #pragma unroll
    for (int c = 0; c < 4; ++c) {
        if (markT[gofs + dd[c]] >= 0) {
            int s = base[4*w4 + c] + gofs;
            if (markT[s] == -1) markT[s] = -3;      // benign same-value race
        }
    }
}

// pass3: degree count filtered to marked nodes (distributed atomics)
__global__ __launch_bounds__(256) void k_pass3(const int* __restrict__ edges,
        const int* __restrict__ markT, int* __restrict__ degCnt) {
    int idx = blockIdx.x*256 + threadIdx.x;
    int g = idx / (NE/4), w4 = idx - g*(NE/4);
    int4 d4 = ((const int4*)(edges + (size_t)g*2*NE + NE))[w4];
    int gofs = g*NN;
    int dd[4] = {d4.x, d4.y, d4.z, d4.w};
    #pragma unroll
    for (int c = 0; c < 4; ++c) {
        int n = gofs + dd[c];
        if (markT[n] != -1) atomicAdd(&degCnt[n], 1);
    }
}

// pass2b: aggregate layer-1 inputs directly at T slots (distributed fp atomics)
__global__ __launch_bounds__(256) void k_pass2b(const int* __restrict__ edges,
        const int* __restrict__ markT, const int* __restrict__ degCnt,
        const float* __restrict__ xg, float* __restrict__ axT) {
    int idx = blockIdx.x*256 + threadIdx.x;
    int g = idx / (NE/4), w4 = idx - g*(NE/4);
    const int* base = edges + (size_t)g*2*NE;
    int4 d4 = ((const int4*)(base + NE))[w4];
    int gofs = g*NN;
    int dd[4] = {d4.x, d4.y, d4.z, d4.w};
    #pragma unroll
    for (int c = 0; c < 4; ++c) {
        int ts = markT[gofs + dd[c]];
        if (ts >= 0) {
            int s = base[4*w4 + c] + gofs;
            float dv = rsqrtf(1.0f + (float)degCnt[s]);
            const float* xr = xg + (size_t)s*FIN;
            float* at = axT + (size_t)ts*FIN;
            #pragma unroll
            for (int f = 0; f < FIN; ++f) unsafeAtomicAdd(&at[f], xr[f]*dv);
        }
    }
}

// Fused layer-1 dense + layer-2 dense over T slots (<= ~720 active rows).
// Self-loop term added during A-tile load: ax = (sum_in + x[n]*dv) * dv.
#define KC 32
__global__ __launch_bounds__(256) void k_h12T(
        const float* __restrict__ axT, const int* __restrict__ Tnodes,
        const int* __restrict__ degCnt, const int* __restrict__ cnts,
        const float* __restrict__ xg,
        const float* __restrict__ W1, const float* __restrict__ b1,
        const float* __restrict__ W2, float* __restrict__ hsT) {
    __shared__ float axs[FIN][128];
    __shared__ float w1s[FIN][128];
    __shared__ float b1s[128];
    __shared__ float dvs[128];
    __shared__ float xs[KC*128];
    __shared__ float wt[KC*64];
    int ntv = cnts[C_NT]; if (ntv > TCAP) ntv = TCAP;
    int jb  = blockIdx.x & 1;
    int m0g = (blockIdx.x >> 1) * 128;
    if (m0g >= ntv) return;
    int tid = threadIdx.x;
    if (tid < 128) {
        b1s[tid] = b1[tid];
        #pragma unroll
        for (int f = 0; f < FIN; ++f) w1s[f][tid] = W1[tid*FIN + f];
    } else {
        int r2 = tid - 128;
        int row = m0g + r2;
        int ok = row < ntv;
        int node = ok ? Tnodes[row] : 0;
        float dvv = ok ? rsqrtf(1.0f + (float)degCnt[node]) : 0.0f;
        dvs[r2] = dvv;
        #pragma unroll
        for (int f = 0; f < FIN; ++f)
            axs[f][r2] = axT[(size_t)row*FIN + f] + xg[(size_t)node*FIN + f]*dvv;
    }
    int tx = tid & 15, ty = tid >> 4;
    int m0 = ty*8;
    int j0 = tx*4;
    int r  = tid >> 1;
    int kq = (tid & 1) * 16;
    int rw  = tid >> 2;
    int kqw = (tid & 3) * 8;
    float a[8][4];
    #pragma unroll
    for (int i = 0; i < 8; ++i)
        #pragma unroll
        for (int j = 0; j < 4; ++j) a[i][j] = 0.f;
    __syncthreads();
    float axr[FIN];
    float dvr = dvs[r];
    #pragma unroll
    for (int f = 0; f < FIN; ++f) axr[f] = axs[f][r] * dvr;

    for (int kh = 0; kh < 128; kh += KC) {
        float4 wv0 = *(const float4*)&W2[(size_t)(jb*64 + rw)*128 + kh + kqw];
        float4 wv1 = *(const float4*)&W2[(size_t)(jb*64 + rw)*128 + kh + kqw + 4];
        float hv[16];
        #pragma unroll
        for (int kk = 0; kk < 16; ++kk) {
            int k1 = kh + kq + kk;
            float sv = b1s[k1];
            #pragma unroll
            for (int f = 0; f < FIN; ++f) sv += axr[f]*w1s[f][k1];
            hv[kk] = fmaxf(sv, 0.0f);
        }
        __syncthreads();
        #pragma unroll
        for (int kk = 0; kk < 16; ++kk) xs[(kq+kk)*128 + r] = hv[kk];
        wt[(kqw+0)*64 + rw] = wv0.x;
        wt[(kqw+1)*64 + rw] = wv0.y;
        wt[(kqw+2)*64 + rw] = wv0.z;
        wt[(kqw+3)*64 + rw] = wv0.w;
        wt[(kqw+4)*64 + rw] = wv1.x;
        wt[(kqw+5)*64 + rw] = wv1.y;
        wt[(kqw+6)*64 + rw] = wv1.z;
        wt[(kqw+7)*64 + rw] = wv1.w;
        __syncthreads();
        for (int k = 0; k < KC; ++k) {
            float4 xa = *(const float4*)&xs[k*128 + m0];
            float4 xb = *(const float4*)&xs[k*128 + m0 + 4];
            float4 wa = *(const float4*)&wt[k*64 + j0];
            float xr[8] = {xa.x,xa.y,xa.z,xa.w,xb.x,xb.y,xb.z,xb.w};
            #pragma unroll
            for (int i = 0; i < 8; ++i) {
                a[i][0] += xr[i]*wa.x;
                a[i][1] += xr[i]*wa.y;
                a[i][2] += xr[i]*wa.z;
                a[i][3] += xr[i]*wa.w;
            }
        }
    }
    #pragma unroll
    for (int i = 0; i < 8; ++i) {
        int row = m0g + m0 + i;
        if (row < ntv) {
            float dv = dvs[m0 + i];
            float4 v0 = make_float4(a[i][0]*dv, a[i][1]*dv, a[i][2]*dv, a[i][3]*dv);
            *(float4*)&hsT[(size_t)row*HID + jb*64 + j0] = v0;
        }
    }
}

// layer-2 aggregation at the 40 positions, from compact hsT rows
__global__ __launch_bounds__(128) void k_aggPT(
        const int* __restrict__ pos2t0, const int* __restrict__ posNode,
        const int* __restrict__ cnts, const int* __restrict__ e0,
        const int* __restrict__ markT, const float* __restrict__ hsT,
        const int* __restrict__ degCnt, const float* __restrict__ b2,
        float* __restrict__ cx40) {
    int p = blockIdx.x;
    int f = threadIdx.x;
    int n = posNode[p];
    int t0 = pos2t0[p];
    float acc = hsT[(size_t)t0*HID + f];        // self-loop term
    int m = cnts[C_E0(t0)]; if (m > E0CAP) m = E0CAP;
    for (int j = 0; j < m; ++j) {
        int s = e0[t0*E0CAP + j];
        int ts = markT[s];
        if (ts >= 0) acc += hsT[(size_t)ts*HID + f];
    }
    float dv = rsqrtf(1.0f + (float)degCnt[n]);
    cx40[(size_t)p*HID + f] = fmaxf(acc*dv + b2[f], 0.0f);
}

// MLP1: block per (batch, 16-output group); 16 lanes per output, shuffle-reduce.
__global__ __launch_bounds__(256) void k_mlp1(
        const float* __restrict__ cx40, const float* __restrict__ actions,
        const float* __restrict__ steps,
        const float* __restrict__ Wp1, const float* __restrict__ bp1,
        float* __restrict__ hm) {
    int b  = blockIdx.x >> 4;
    int jg = blockIdx.x & 15;
    int t  = threadIdx.x;
    __shared__ float c[PROJ_IN];
    for (int i = t; i < 5*HID; i += 256)
        c[i] = cx40[(size_t)b*5*HID + i];
    if (t < ALAST) c[5*HID + t] = actions[b*ALAST + t];
    if (t == ALAST) c[5*HID + ALAST] = steps[b];
    __syncthreads();
    int o = t >> 4, sub = t & 15;
    int j = jg*16 + o;
    const float* wr = Wp1 + (size_t)j*PROJ_IN;
    float s = 0.f;
    for (int k = sub; k < PROJ_IN; k += 16) s += c[k]*wr[k];
    #pragma unroll
    for (int d = 8; d; d >>= 1) s += __shfl_down(s, d, 16);
    if (sub == 0) hm[b*EMB + j] = fmaxf(s + bp1[j], 0.f);
}

// MLP2
__global__ __launch_bounds__(256) void k_mlp2(
        const float* __restrict__ hm, const float* __restrict__ Wp2,
        const float* __restrict__ bp2, float* __restrict__ out) {
    int b  = blockIdx.x >> 4;
    int jg = blockIdx.x & 15;
    int t  = threadIdx.x;
    __shared__ float c[EMB];
    if (t < EMB) c[t] = hm[b*EMB + t];
    __syncthreads();
    int o = t >> 4, sub = t & 15;
    int j = jg*16 + o;
    const float* wr = Wp2 + (size_t)j*EMB;
    float s = 0.f;
    for (int k = sub; k < EMB; k += 16) s += c[k]*wr[k];
    #pragma unroll
    for (int d = 8; d; d >>= 1) s += __shfl_down(s, d, 16);
    if (sub == 0) out[b*EMB + j] = s + bp2[j];
}

extern "C" void kernel_launch(void* const* d_in, const int* in_sizes, int n_in,
                              void* d_out, int out_size, void* d_ws, size_t ws_size,
                              hipStream_t stream) {
    const float* graph_x = (const float*)d_in[0];
    const int*   edges   = (const int*)d_in[1];
    const int*   pos     = (const int*)d_in[2];
    const int*   avail   = (const int*)d_in[3];
    const float* actions = (const float*)d_in[4];
    const float* steps   = (const float*)d_in[5];
    const float* W1  = (const float*)d_in[6];
    const float* b1  = (const float*)d_in[7];
    const float* W2  = (const float*)d_in[8];
    const float* b2  = (const float*)d_in[9];
    const float* Wp1 = (const float*)d_in[10];
    const float* bp1 = (const float*)d_in[11];
    const float* Wp2 = (const float*)d_in[12];
    const float* bp2 = (const float*)d_in[13];
    float* out = (float*)d_out;

    char* ws = (char*)d_ws;
    size_t off = 0;
    #define ALLOC(ptrname, type, nelem) \
        type* ptrname = (type*)(ws + off); off = (off + (size_t)(nelem)*sizeof(type) + 255) & ~(size_t)255;
    // memset A region (-1): markT
    ALLOC(markT,   int,   NNODES)
    // memset B region (0): degCnt, cnts, axT
    ALLOC(degCnt,  int,   NNODES)
    ALLOC(cnts,    int,   1024)
    ALLOC(axT,     float, (size_t)(TCAP+128)*FIN)
    char* msB_end = ws + off;
    // un-cleared scratch
    ALLOC(Tnodes,  int,   TCAP)
    ALLOC(pos2t0,  int,   NPOS)
    ALLOC(posNode, int,   NPOS)
    ALLOC(e0,      int,   NPOS*E0CAP)
    ALLOC(hsT,     float, (size_t)TCAP*HID)
    ALLOC(cx40,    float, (size_t)NPOS*HID)
    ALLOC(hm,      float, (size_t)NB*EMB)
    #undef ALLOC

    hipMemsetAsync(markT, 0xFF, (size_t)NNODES*4, stream);                  // markT = -1
    hipMemsetAsync(degCnt, 0x00, (size_t)(msB_end - (char*)degCnt), stream);// degCnt..axT = 0

    k_mark<<<1, 64, 0, stream>>>(avail, pos, markT, Tnodes, cnts, pos2t0, posNode);
    k_pass1<<<NEDGE/4/256, 256, 0, stream>>>(edges, markT, cnts, e0);
    k_dedup<<<NPOS, 256, 0, stream>>>(e0, cnts, markT, Tnodes);
    k_pass2a<<<NEDGE/4/256, 256, 0, stream>>>(edges, markT);
    k_pass3<<<NEDGE/4/256, 256, 0, stream>>>(edges, markT, degCnt);
    k_pass2b<<<NEDGE/4/256, 256, 0, stream>>>(edges, markT, degCnt, graph_x, axT);
    k_h12T<<<2*((TCAP+127)/128), 256, 0, stream>>>(axT, Tnodes, degCnt, cnts,
                                                   graph_x, W1, b1, W2, hsT);
    k_aggPT<<<NPOS, 128, 0, stream>>>(pos2t0, posNode, cnts, e0, markT, hsT,
                                      degCnt, b2, cx40);
    k_mlp1<<<NB*16, 256, 0, stream>>>(cx40, actions, steps, Wp1, bp1, hm);
    k_mlp2<<<NB*16, 256, 0, stream>>>(hm, Wp2, bp2, out);
}